// Round 1
// baseline (391.473 us; speedup 1.0000x reference)
//
#include <hip/hip_runtime.h>

// Embedding gather: out[r, :] = table[idx[r], :]
// rows = BATCH*NUM_FEATS = 819200, D = 64 floats (256 B) per row.
// 16 lanes per row, float4 per lane -> 16 B/lane, 256 B per row segment.

#define EMBED_DIM 64
#define LANES_PER_ROW 16  // EMBED_DIM * 4 bytes / 16 bytes per lane

__global__ __launch_bounds__(256) void hh_embed_gather(
    const int* __restrict__ idx,
    const float4* __restrict__ table,   // table as float4: V x 16
    float4* __restrict__ out,           // out as float4:  rows x 16
    int n_rows)
{
    int tid  = blockIdx.x * blockDim.x + threadIdx.x;
    int row  = tid >> 4;        // / LANES_PER_ROW
    int lane = tid & 15;        // % LANES_PER_ROW
    if (row >= n_rows) return;

    int t = idx[row];           // broadcast within the 16-lane group (same cacheline)
    long long src = (long long)t   * LANES_PER_ROW + lane;
    long long dst = (long long)row * LANES_PER_ROW + lane;
    out[dst] = table[src];
}

extern "C" void kernel_launch(void* const* d_in, const int* in_sizes, int n_in,
                              void* d_out, int out_size, void* d_ws, size_t ws_size,
                              hipStream_t stream) {
    const int*   idx   = (const int*)d_in[0];     // [B*F] int32
    const float* table = (const float*)d_in[1];   // [V, 64] fp32
    float*       out   = (float*)d_out;           // [B*F, 64] fp32

    int n_rows = in_sizes[0];                     // 819200
    long long total_threads = (long long)n_rows * LANES_PER_ROW;
    int block = 256;
    int grid  = (int)((total_threads + block - 1) / block);

    hh_embed_gather<<<grid, block, 0, stream>>>(
        idx, (const float4*)table, (float4*)out, n_rows);
}